// Round 2
// baseline (924.481 us; speedup 1.0000x reference)
//
#include <hip/hip_runtime.h>

typedef unsigned short u16;
typedef unsigned int u32;

#define NEG_SLOPE 0.2f

__device__ __forceinline__ float bfu(u16 v) { return __uint_as_float(((u32)v) << 16); }
__device__ __forceinline__ float bflo(u32 u) { return __uint_as_float(u << 16); }
__device__ __forceinline__ float bfhi(u32 u) { return __uint_as_float(u & 0xffff0000u); }
__device__ __forceinline__ u16 f2bf(float f) {
  u32 x = __float_as_uint(f);
  return (u16)((x + 0x7fffu + ((x >> 16) & 1u)) >> 16);
}
// generic scalar float load: isbf ? bf16[idx] : f32[idx]
__device__ __forceinline__ float loadf(const void* p, int idx, int isbf) {
  return isbf ? bfu(((const u16*)p)[idx]) : ((const float*)p)[idx];
}

// ---------------- dtype detection ----------------
// bf16 data: low u16 of each u32 is a genuine ~N(0,1) bf16 -> exponent field in
// [0x60,0x90] essentially always. f32 data: low 16 bits are mantissa bits ->
// exponent field ~uniform -> ~19% hit the window. Threshold at 50%.
__global__ __launch_bounds__(256) void detect_dtype(const u32* __restrict__ w,
                                                    int nwords, int* __restrict__ flag) {
  __shared__ int cnt;
  if (threadIdx.x == 0) cnt = 0;
  __syncthreads();
  int c = 0;
  for (int i = threadIdx.x; i < nwords; i += 256) {
    u32 e = (w[i] >> 7) & 0xFFu;  // exponent field of low-half-as-bf16
    c += (e >= 0x60u && e <= 0x90u) ? 1 : 0;
  }
  atomicAdd(&cnt, c);
  __syncthreads();
  if (threadIdx.x == 0) flag[0] = (cnt * 2 > nwords) ? 1 : 0;  // 1 = bf16
}

// ---------------- CSR build ----------------

__global__ __launch_bounds__(256) void zero_i32(int* __restrict__ p, int n) {
  int i = blockIdx.x * 256 + threadIdx.x;
  if (i < n) p[i] = 0;
}

__global__ __launch_bounds__(256) void hist_kernel(const int* __restrict__ dst,
                                                   int* __restrict__ counts, int E) {
  int e = blockIdx.x * 256 + threadIdx.x;
  if (e < E) atomicAdd(&counts[dst[e]], 1);
}

__global__ __launch_bounds__(256) void scan1(const int* __restrict__ counts,
                                             int* __restrict__ indptr,
                                             int* __restrict__ bsum, int N) {
  __shared__ int sh[256];
  int t = threadIdx.x;
  int idx = blockIdx.x * 256 + t;
  int v = (idx < N) ? counts[idx] : 0;
  sh[t] = v;
  __syncthreads();
  for (int off = 1; off < 256; off <<= 1) {
    int y = (t >= off) ? sh[t - off] : 0;
    __syncthreads();
    sh[t] += y;
    __syncthreads();
  }
  if (idx < N) indptr[idx] = sh[t] - v;  // exclusive, pre-offset
  if (t == 255) bsum[blockIdx.x] = sh[255];
}

__global__ void scan2(int* bsum, int NB) {
  if (blockIdx.x == 0 && threadIdx.x == 0) {
    int run = 0;
    for (int b = 0; b < NB; ++b) { int s = bsum[b]; bsum[b] = run; run += s; }
  }
}

__global__ __launch_bounds__(256) void scan3(int* __restrict__ indptr,
                                             const int* __restrict__ boff,
                                             int* __restrict__ cursor, int N, int E) {
  int idx = blockIdx.x * 256 + threadIdx.x;
  if (idx < N) {
    int v = indptr[idx] + boff[blockIdx.x];
    indptr[idx] = v;
    cursor[idx] = v;
  }
  if (idx == 0) indptr[N] = E;
}

__global__ __launch_bounds__(256) void scatter_kernel(const int* __restrict__ src,
                                                      const int* __restrict__ dst,
                                                      int* __restrict__ cursor,
                                                      int* __restrict__ ssrc, int E) {
  int e = blockIdx.x * 256 + threadIdx.x;
  if (e < E) {
    int d = dst[e];
    int pos = atomicAdd(&cursor[d], 1);
    ssrc[pos] = src[e];
  }
}

// ---------------- weight transpose (W[Dout][K] -> f32 WT[K][Dout]) ----------------

__global__ __launch_bounds__(256) void transpose_w(const void* __restrict__ W,
                                                   float* __restrict__ WT, int Dout, int K,
                                                   const int* __restrict__ dflag) {
  const int isbf = dflag[0];
  int idx = blockIdx.x * 256 + threadIdx.x;
  if (idx < Dout * K) {
    int j = idx / K, k = idx % K;
    WT[k * Dout + j] = loadf(W, idx, isbf);
  }
}

// ---------------- GEMM: H[N,128] = X[N,K] @ WT[K,128], f32 accumulate ----------------
// block: 64 rows x 128 cols; thread: 8 rows x 4 cols; K staged in 128-chunks.
// DYN=1: X dtype chosen at runtime by dflag (bf16 or f32). DYN=0: X is f32.

template <int DYN, int K>
__global__ __launch_bounds__(256) void gemm_kernel(const void* __restrict__ Xv,
                                                   const float* __restrict__ WT,
                                                   float* __restrict__ H, int N,
                                                   const int* __restrict__ dflag) {
  const int isbf = DYN ? dflag[0] : 0;
  __shared__ float xs[64][132];
  const int tid = threadIdx.x;
  const int row0 = blockIdx.x * 64;
  const int cg = tid & 31;   // col group: cols cg*4..cg*4+3
  const int rg = tid >> 5;   // row group: rows rg*8..rg*8+7

  float acc[8][4];
#pragma unroll
  for (int r = 0; r < 8; ++r)
#pragma unroll
    for (int c = 0; c < 4; ++c) acc[r][c] = 0.f;

  for (int kt = 0; kt < K; kt += 128) {
#pragma unroll
    for (int i = 0; i < 4; ++i) {
      int c = tid + i * 256;
      int row = c >> 4;   // 16 chunks of 8 per row
      int ci = c & 15;
      int grow = row0 + row;
      float v[8];
      if (grow < N) {
        if (isbf) {
          const u16* X = (const u16*)Xv;
          uint4 u = *(const uint4*)(X + (size_t)grow * K + kt + ci * 8);
          v[0] = bflo(u.x); v[1] = bfhi(u.x);
          v[2] = bflo(u.y); v[3] = bfhi(u.y);
          v[4] = bflo(u.z); v[5] = bfhi(u.z);
          v[6] = bflo(u.w); v[7] = bfhi(u.w);
        } else {
          const float* X = (const float*)Xv;
          float4 f0 = *(const float4*)(X + (size_t)grow * K + kt + ci * 8);
          float4 f1 = *(const float4*)(X + (size_t)grow * K + kt + ci * 8 + 4);
          v[0] = f0.x; v[1] = f0.y; v[2] = f0.z; v[3] = f0.w;
          v[4] = f1.x; v[5] = f1.y; v[6] = f1.z; v[7] = f1.w;
        }
      } else {
#pragma unroll
        for (int j = 0; j < 8; ++j) v[j] = 0.f;
      }
      *(float4*)&xs[row][ci * 8] = make_float4(v[0], v[1], v[2], v[3]);
      *(float4*)&xs[row][ci * 8 + 4] = make_float4(v[4], v[5], v[6], v[7]);
    }
    __syncthreads();

    for (int k = 0; k < 128; k += 4) {
      float4 a[8];
#pragma unroll
      for (int r = 0; r < 8; ++r) a[r] = *(const float4*)&xs[rg * 8 + r][k];
#pragma unroll
      for (int j = 0; j < 4; ++j) {
        float4 w = *(const float4*)(WT + (size_t)(kt + k + j) * 128 + cg * 4);
#pragma unroll
        for (int r = 0; r < 8; ++r) {
          float av = ((const float*)&a[r])[j];
          acc[r][0] = fmaf(av, w.x, acc[r][0]);
          acc[r][1] = fmaf(av, w.y, acc[r][1]);
          acc[r][2] = fmaf(av, w.z, acc[r][2]);
          acc[r][3] = fmaf(av, w.w, acc[r][3]);
        }
      }
    }
    __syncthreads();
  }

#pragma unroll
  for (int r = 0; r < 8; ++r) {
    int grow = row0 + rg * 8 + r;
    if (grow < N) {
      *(float4*)(H + (size_t)grow * 128 + cg * 4) =
          make_float4(acc[r][0], acc[r][1], acc[r][2], acc[r][3]);
    }
  }
}

// ---------------- el/er: dot(h[n], al), dot(h[n], ar), one wave per node ----------------

__global__ __launch_bounds__(256) void el_er_kernel(const float* __restrict__ H,
                                                    const void* __restrict__ al,
                                                    const void* __restrict__ ar,
                                                    float* __restrict__ el,
                                                    float* __restrict__ er, int N,
                                                    const int* __restrict__ dflag) {
  const int isbf = dflag[0];
  int tid = threadIdx.x;
  int n = blockIdx.x * 4 + (tid >> 6);
  int lane = tid & 63;
  if (n >= N) return;
  float h0 = H[(size_t)n * 128 + lane];
  float h1 = H[(size_t)n * 128 + 64 + lane];
  float al0 = loadf(al, lane, isbf), al1 = loadf(al, 64 + lane, isbf);
  float ar0 = loadf(ar, lane, isbf), ar1 = loadf(ar, 64 + lane, isbf);
  float pl = h0 * al0 + h1 * al1;
  float pr = h0 * ar0 + h1 * ar1;
  for (int off = 32; off; off >>= 1) {
    pl += __shfl_xor(pl, off, 64);
    pr += __shfl_xor(pr, off, 64);
  }
  if (lane == 0) {
    el[n] = pl;
    er[n] = pr;
  }
}

// ---------------- aggregation: one wave per dst node, online softmax ----------------
// MODE 0: out = f32 elu(agg + bias)        (layer 1 -> x, ws, always f32)
// MODE 1: out = (agg + bias) in output dtype (layer 2 -> d_out, bf16 or f32 per flag)

template <int MODE>
__global__ __launch_bounds__(256) void agg_kernel(const float* __restrict__ H,
                                                  const float* __restrict__ el,
                                                  const float* __restrict__ er,
                                                  const int* __restrict__ indptr,
                                                  const int* __restrict__ ssrc,
                                                  const void* __restrict__ bias,
                                                  void* __restrict__ outv, int N,
                                                  const int* __restrict__ dflag) {
  const int isbf = dflag[0];
  int tid = threadIdx.x;
  int n = blockIdx.x * 4 + (tid >> 6);
  int lane = tid & 63;
  if (n >= N) return;

  int beg = indptr[n];
  int end = indptr[n + 1];
  float ern = er[n];

  float m = -INFINITY, l = 0.f, a0 = 0.f, a1 = 0.f;
  for (int p = beg; p < end; ++p) {
    int s = ssrc[p];
    float sc = el[s] + ern;
    sc = (sc > 0.f) ? sc : NEG_SLOPE * sc;
    float mn = fmaxf(m, sc);
    float corr = __expf(m - mn);  // 0 on first edge (m = -inf)
    float pe = __expf(sc - mn);
    float h0 = H[(size_t)s * 128 + lane];
    float h1 = H[(size_t)s * 128 + 64 + lane];
    l = l * corr + pe;
    a0 = a0 * corr + pe * h0;
    a1 = a1 * corr + pe * h1;
    m = mn;
  }
  float inv = (l > 0.f) ? 1.f / l : 0.f;
  float o0 = a0 * inv + loadf(bias, lane, isbf);
  float o1 = a1 * inv + loadf(bias, 64 + lane, isbf);
  if (MODE == 0) {
    float* out = (float*)outv;
    out[(size_t)n * 128 + lane] = (o0 > 0.f) ? o0 : (__expf(o0) - 1.f);
    out[(size_t)n * 128 + 64 + lane] = (o1 > 0.f) ? o1 : (__expf(o1) - 1.f);
  } else {
    if (isbf) {
      u16* out = (u16*)outv;
      out[(size_t)n * 128 + lane] = f2bf(o0);
      out[(size_t)n * 128 + 64 + lane] = f2bf(o1);
    } else {
      float* out = (float*)outv;
      out[(size_t)n * 128 + lane] = o0;
      out[(size_t)n * 128 + 64 + lane] = o1;
    }
  }
}

// ---------------- launch ----------------

extern "C" void kernel_launch(void* const* d_in, const int* in_sizes, int n_in,
                              void* d_out, int out_size, void* d_ws, size_t ws_size,
                              hipStream_t stream) {
  const int IN_FEATS = 256, HID = 128;
  const void* features = d_in[0];
  const int* src = (const int*)d_in[1];
  const int* dst = (const int*)d_in[2];
  const void* W1 = d_in[3];
  const void* al1 = d_in[4];
  const void* ar1 = d_in[5];
  const void* b1 = d_in[6];
  const void* W2 = d_in[7];
  const void* al2 = d_in[8];
  const void* ar2 = d_in[9];
  const void* b2 = d_in[10];

  const int N = in_sizes[0] / IN_FEATS;  // 100000
  const int E = in_sizes[1];             // 1600000

  // workspace carve
  char* p = (char*)d_ws;
  auto alloc = [&](size_t bytes) -> void* {
    void* q = (void*)p;
    p += (bytes + 255) & ~(size_t)255;
    return q;
  };
  int* dflag = (int*)alloc(256);
  float* WT1 = (float*)alloc((size_t)IN_FEATS * HID * 4);
  float* WT2 = (float*)alloc((size_t)HID * HID * 4);
  float* h = (float*)alloc((size_t)N * HID * 4);
  float* x = (float*)alloc((size_t)N * HID * 4);
  float* el = (float*)alloc((size_t)N * 4);
  float* er = (float*)alloc((size_t)N * 4);
  int* counts = (int*)alloc((size_t)N * 4);
  int* indptr = (int*)alloc((size_t)(N + 1) * 4);
  int* cursor = (int*)alloc((size_t)N * 4);
  int* bsum = (int*)alloc((size_t)((N + 255) / 256) * 4);
  int* ssrc = (int*)alloc((size_t)E * 4);

  const int NB = (N + 255) / 256;    // 391
  const int EB = (E + 255) / 256;    // 6250
  const int GEMM_B = (N + 63) / 64;  // 1563
  const int NODE_B = (N + 3) / 4;    // 25000

  // dtype flag (bf16 vs f32) from feature bit patterns
  detect_dtype<<<1, 256, 0, stream>>>((const u32*)features, 4096, dflag);

  // CSR by dst (shared by both layers)
  zero_i32<<<NB, 256, 0, stream>>>(counts, N);
  hist_kernel<<<EB, 256, 0, stream>>>(dst, counts, E);
  scan1<<<NB, 256, 0, stream>>>(counts, indptr, bsum, N);
  scan2<<<1, 64, 0, stream>>>(bsum, NB);
  scan3<<<NB, 256, 0, stream>>>(indptr, bsum, cursor, N, E);
  scatter_kernel<<<EB, 256, 0, stream>>>(src, dst, cursor, ssrc, E);

  // layer 1
  transpose_w<<<(HID * IN_FEATS + 255) / 256, 256, 0, stream>>>(W1, WT1, HID, IN_FEATS, dflag);
  gemm_kernel<1, 256><<<GEMM_B, 256, 0, stream>>>(features, WT1, h, N, dflag);
  el_er_kernel<<<NODE_B, 256, 0, stream>>>(h, al1, ar1, el, er, N, dflag);
  agg_kernel<0><<<NODE_B, 256, 0, stream>>>(h, el, er, indptr, ssrc, b1, (void*)x, N, dflag);

  // layer 2
  transpose_w<<<(HID * HID + 255) / 256, 256, 0, stream>>>(W2, WT2, HID, HID, dflag);
  gemm_kernel<0, 128><<<GEMM_B, 256, 0, stream>>>((const void*)x, WT2, h, N, dflag);
  el_er_kernel<<<NODE_B, 256, 0, stream>>>(h, al2, ar2, el, er, N, dflag);
  agg_kernel<1><<<NODE_B, 256, 0, stream>>>(h, el, er, indptr, ssrc, b2, d_out, N, dflag);
}

// Round 3
// 822.780 us; speedup vs baseline: 1.1236x; 1.1236x over previous
//
#include <hip/hip_runtime.h>

typedef unsigned short u16;
typedef unsigned int u32;

#define NEG_SLOPE 0.2f

using short8 = __attribute__((ext_vector_type(8))) short;
using float4v = __attribute__((ext_vector_type(4))) float;

__device__ __forceinline__ float bfu(u16 v) { return __uint_as_float(((u32)v) << 16); }
__device__ __forceinline__ float bflo(u32 u) { return __uint_as_float(u << 16); }
__device__ __forceinline__ float bfhi(u32 u) { return __uint_as_float(u & 0xffff0000u); }
__device__ __forceinline__ u16 f2bf(float f) {
  u32 x = __float_as_uint(f);
  return (u16)((x + 0x7fffu + ((x >> 16) & 1u)) >> 16);
}
__device__ __forceinline__ float loadf(const void* p, int idx, int isbf) {
  return isbf ? bfu(((const u16*)p)[idx]) : ((const float*)p)[idx];
}

// ---------------- dtype detection (bf16 vs f32 inputs) ----------------
__global__ __launch_bounds__(256) void detect_dtype(const u32* __restrict__ w,
                                                    int nwords, int* __restrict__ flag) {
  __shared__ int cnt;
  if (threadIdx.x == 0) cnt = 0;
  __syncthreads();
  int c = 0;
  for (int i = threadIdx.x; i < nwords; i += 256) {
    u32 e = (w[i] >> 7) & 0xFFu;  // exponent of low-half-as-bf16
    c += (e >= 0x60u && e <= 0x90u) ? 1 : 0;
  }
  atomicAdd(&cnt, c);
  __syncthreads();
  if (threadIdx.x == 0) flag[0] = (cnt * 2 > nwords) ? 1 : 0;  // 1 = bf16
}

// ---------------- features -> bf16 (copy if already bf16) ----------------
__global__ __launch_bounds__(256) void conv_feat(const void* __restrict__ F,
                                                 u16* __restrict__ Xbf, int nelem,
                                                 const int* __restrict__ dflag) {
  const int isbf = dflag[0];
  int i = blockIdx.x * 256 + threadIdx.x;  // uint4 index (8 elems)
  if (i * 8 >= nelem) return;
  if (isbf) {
    ((uint4*)Xbf)[i] = ((const uint4*)F)[i];
  } else {
    const float* Ff = (const float*)F;
    float4 a = ((const float4*)Ff)[i * 2];
    float4 b = ((const float4*)Ff)[i * 2 + 1];
    u32 w0 = (u32)f2bf(a.x) | ((u32)f2bf(a.y) << 16);
    u32 w1 = (u32)f2bf(a.z) | ((u32)f2bf(a.w) << 16);
    u32 w2 = (u32)f2bf(b.x) | ((u32)f2bf(b.y) << 16);
    u32 w3 = (u32)f2bf(b.z) | ((u32)f2bf(b.w) << 16);
    ((uint4*)Xbf)[i] = make_uint4(w0, w1, w2, w3);
  }
}

// ---------------- CSR build ----------------

__global__ __launch_bounds__(256) void zero_i32(int* __restrict__ p, int n) {
  int i = blockIdx.x * 256 + threadIdx.x;
  if (i < n) p[i] = 0;
}

__global__ __launch_bounds__(256) void hist_kernel(const int* __restrict__ dst,
                                                   int* __restrict__ counts, int E) {
  int e = blockIdx.x * 256 + threadIdx.x;
  if (e < E) atomicAdd(&counts[dst[e]], 1);
}

__global__ __launch_bounds__(256) void scan1(const int* __restrict__ counts,
                                             int* __restrict__ indptr,
                                             int* __restrict__ bsum, int N) {
  __shared__ int sh[256];
  int t = threadIdx.x;
  int idx = blockIdx.x * 256 + t;
  int v = (idx < N) ? counts[idx] : 0;
  sh[t] = v;
  __syncthreads();
  for (int off = 1; off < 256; off <<= 1) {
    int y = (t >= off) ? sh[t - off] : 0;
    __syncthreads();
    sh[t] += y;
    __syncthreads();
  }
  if (idx < N) indptr[idx] = sh[t] - v;  // exclusive, pre-offset
  if (t == 255) bsum[blockIdx.x] = sh[255];
}

// parallel single-block exclusive scan of block sums (NB <= 512)
__global__ __launch_bounds__(512) void scan2par(int* __restrict__ bsum, int NB) {
  __shared__ int sh[512];
  int t = threadIdx.x;
  int v = (t < NB) ? bsum[t] : 0;
  sh[t] = v;
  __syncthreads();
  for (int off = 1; off < 512; off <<= 1) {
    int y = (t >= off) ? sh[t - off] : 0;
    __syncthreads();
    sh[t] += y;
    __syncthreads();
  }
  if (t < NB) bsum[t] = sh[t] - v;  // exclusive
}

__global__ __launch_bounds__(256) void scan3(int* __restrict__ indptr,
                                             const int* __restrict__ boff,
                                             int* __restrict__ cursor, int N, int E) {
  int idx = blockIdx.x * 256 + threadIdx.x;
  if (idx < N) {
    int v = indptr[idx] + boff[blockIdx.x];
    indptr[idx] = v;
    cursor[idx] = v;
  }
  if (idx == 0) indptr[N] = E;
}

__global__ __launch_bounds__(256) void scatter_kernel(const int* __restrict__ src,
                                                      const int* __restrict__ dst,
                                                      int* __restrict__ cursor,
                                                      int* __restrict__ ssrc, int E) {
  int e = blockIdx.x * 256 + threadIdx.x;
  if (e < E) {
    int d = dst[e];
    int pos = atomicAdd(&cursor[d], 1);
    ssrc[pos] = src[e];
  }
}

// ---------------- B-fragment swizzle buffer ----------------
// Bsw[t][c][lane] : uint4 = 8 bf16, element j = B[k=t*32+(lane>>4)*8+j][n=c*16+(lane&15)]
// where B[k][n] = W[n][k] (W is [128][K] row-major, bf16 or f32 per dflag).
__global__ __launch_bounds__(256) void bsw_build(const void* __restrict__ W,
                                                 u16* __restrict__ Bsw, int K,
                                                 const int* __restrict__ dflag) {
  const int isbf = dflag[0];
  int t = blockIdx.x * 256 + threadIdx.x;
  int total = (K / 32) * 8 * 64;
  if (t >= total) return;
  int lane = t & 63;
  int c = (t >> 6) & 7;
  int ktile = t >> 9;
  int n = lane & 15, q = lane >> 4;
  int col = c * 16 + n;  // output-feature index (row of W)
  u16 vals[8];
#pragma unroll
  for (int j = 0; j < 8; ++j) {
    int k = ktile * 32 + q * 8 + j;
    int idx = col * K + k;
    vals[j] = isbf ? ((const u16*)W)[idx] : f2bf(((const float*)W)[idx]);
  }
  *(uint4*)(Bsw + (size_t)t * 8) = *(uint4*)vals;
}

// ---------------- MFMA GEMM: H[N,128] = X[N,K] @ W^T, X bf16, W swizzled ----------------
// block = 4 waves; each wave does 16 rows x 128 cols (8 tiles of 16x16x32-mfma).
// Outputs: H f32 row-major AND Hb packed-bf16 row-major.
template <int K>
__global__ __launch_bounds__(256) void gemm_mfma(const u16* __restrict__ Xbf,
                                                 const u16* __restrict__ Bsw,
                                                 float* __restrict__ H,
                                                 u16* __restrict__ Hb, int N) {
  int tid = threadIdx.x;
  int w = tid >> 6, lane = tid & 63;
  int n = lane & 15, q = lane >> 4;
  int row0 = blockIdx.x * 64 + w * 16;
  int m = row0 + n;
  int mclamp = (m < N) ? m : 0;  // OOB rows read row 0; their outputs are discarded

  float4v acc[8];
#pragma unroll
  for (int c = 0; c < 8; ++c) acc[c] = (float4v){0.f, 0.f, 0.f, 0.f};

  const u16* arow = Xbf + (size_t)mclamp * K + q * 8;
#pragma unroll
  for (int t = 0; t < K / 32; ++t) {
    uint4 aw = *(const uint4*)(arow + t * 32);
    short8 af = *(short8*)&aw;
    const uint4* bt = (const uint4*)Bsw + ((size_t)t * 8) * 64 + lane;
#pragma unroll
    for (int c = 0; c < 8; ++c) {
      uint4 bw = bt[c * 64];
      short8 bf = *(short8*)&bw;
      acc[c] = __builtin_amdgcn_mfma_f32_16x16x32_bf16(af, bf, acc[c], 0, 0, 0);
    }
  }

#pragma unroll
  for (int c = 0; c < 8; ++c) {
#pragma unroll
    for (int r = 0; r < 4; ++r) {
      int row = row0 + q * 4 + r;  // D: col = lane&15, row = quad*4 + reg
      if (row < N) {
        float v = acc[c][r];
        H[(size_t)row * 128 + c * 16 + n] = v;
        Hb[(size_t)row * 128 + c * 16 + n] = f2bf(v);
      }
    }
  }
}

// ---------------- el/er from f32 h, one wave per node ----------------
__global__ __launch_bounds__(256) void el_er_kernel(const float* __restrict__ H,
                                                    const void* __restrict__ al,
                                                    const void* __restrict__ ar,
                                                    float* __restrict__ el,
                                                    float* __restrict__ er, int N,
                                                    const int* __restrict__ dflag) {
  const int isbf = dflag[0];
  int tid = threadIdx.x;
  int n = blockIdx.x * 4 + (tid >> 6);
  int lane = tid & 63;
  if (n >= N) return;
  float h0 = H[(size_t)n * 128 + lane];
  float h1 = H[(size_t)n * 128 + 64 + lane];
  float pl = h0 * loadf(al, lane, isbf) + h1 * loadf(al, 64 + lane, isbf);
  float pr = h0 * loadf(ar, lane, isbf) + h1 * loadf(ar, 64 + lane, isbf);
  for (int off = 32; off; off >>= 1) {
    pl += __shfl_xor(pl, off, 64);
    pr += __shfl_xor(pr, off, 64);
  }
  if (lane == 0) {
    el[n] = pl;
    er[n] = pr;
  }
}

// ---------------- aggregation: one wave per dst node, online softmax ----------------
// Gathers packed-bf16 rows (one u32 per lane = cols 2*lane, 2*lane+1).
// MODE 0: x (packed bf16) = elu(agg + bias)        (layer 1)
// MODE 1: d_out = agg + bias (bf16-packed or f32 per dflag)
template <int MODE>
__global__ __launch_bounds__(256) void agg_kernel(const u32* __restrict__ Hb,
                                                  const float* __restrict__ el,
                                                  const float* __restrict__ er,
                                                  const int* __restrict__ indptr,
                                                  const int* __restrict__ ssrc,
                                                  const void* __restrict__ bias,
                                                  void* __restrict__ outv, int N,
                                                  const int* __restrict__ dflag) {
  const int isbf = dflag[0];
  int tid = threadIdx.x;
  int n = blockIdx.x * 4 + (tid >> 6);
  int lane = tid & 63;
  if (n >= N) return;

  int beg = indptr[n];
  int end = indptr[n + 1];
  float ern = er[n];

  float m = -INFINITY, l = 0.f, a0 = 0.f, a1 = 0.f;
  int s = (beg < end) ? ssrc[beg] : 0;
  for (int p = beg; p < end; ++p) {
    int snext = (p + 1 < end) ? ssrc[p + 1] : 0;  // prefetch next src id
    float sc = el[s] + ern;
    u32 hw = Hb[(size_t)s * 64 + lane];
    sc = (sc > 0.f) ? sc : NEG_SLOPE * sc;
    float mn = fmaxf(m, sc);
    float corr = __expf(m - mn);  // 0 on first edge (m = -inf)
    float pe = __expf(sc - mn);
    float h0 = bflo(hw), h1 = bfhi(hw);
    l = l * corr + pe;
    a0 = a0 * corr + pe * h0;
    a1 = a1 * corr + pe * h1;
    m = mn;
    s = snext;
  }
  float inv = (l > 0.f) ? 1.f / l : 0.f;
  float o0 = a0 * inv + loadf(bias, 2 * lane, isbf);
  float o1 = a1 * inv + loadf(bias, 2 * lane + 1, isbf);
  if (MODE == 0) {
    o0 = (o0 > 0.f) ? o0 : (__expf(o0) - 1.f);
    o1 = (o1 > 0.f) ? o1 : (__expf(o1) - 1.f);
    ((u32*)outv)[(size_t)n * 64 + lane] = (u32)f2bf(o0) | ((u32)f2bf(o1) << 16);
  } else {
    if (isbf) {
      ((u32*)outv)[(size_t)n * 64 + lane] = (u32)f2bf(o0) | ((u32)f2bf(o1) << 16);
    } else {
      ((float2*)outv)[(size_t)n * 64 + lane] = make_float2(o0, o1);
    }
  }
}

// ---------------- launch ----------------

extern "C" void kernel_launch(void* const* d_in, const int* in_sizes, int n_in,
                              void* d_out, int out_size, void* d_ws, size_t ws_size,
                              hipStream_t stream) {
  const int IN_FEATS = 256, HID = 128;
  const void* features = d_in[0];
  const int* src = (const int*)d_in[1];
  const int* dst = (const int*)d_in[2];
  const void* W1 = d_in[3];
  const void* al1 = d_in[4];
  const void* ar1 = d_in[5];
  const void* b1 = d_in[6];
  const void* W2 = d_in[7];
  const void* al2 = d_in[8];
  const void* ar2 = d_in[9];
  const void* b2 = d_in[10];

  const int N = in_sizes[0] / IN_FEATS;  // 100000
  const int E = in_sizes[1];             // 1600000

  char* p = (char*)d_ws;
  auto alloc = [&](size_t bytes) -> void* {
    void* q = (void*)p;
    p += (bytes + 255) & ~(size_t)255;
    return q;
  };
  int* dflag = (int*)alloc(256);
  u16* Xbf = (u16*)alloc((size_t)N * IN_FEATS * 2);   // 51.2 MB
  u16* Bsw1 = (u16*)alloc((size_t)(IN_FEATS / 32) * 8 * 64 * 8 * 2);  // 64 KB
  u16* Bsw2 = (u16*)alloc((size_t)(HID / 32) * 8 * 64 * 8 * 2);       // 32 KB
  float* h = (float*)alloc((size_t)N * HID * 4);      // 51.2 MB
  u16* hb = (u16*)alloc((size_t)N * HID * 2);         // 25.6 MB
  u16* x = (u16*)alloc((size_t)N * HID * 2);          // 25.6 MB
  float* el = (float*)alloc((size_t)N * 4);
  float* er = (float*)alloc((size_t)N * 4);
  int* counts = (int*)alloc((size_t)N * 4);
  int* indptr = (int*)alloc((size_t)(N + 1) * 4);
  int* cursor = (int*)alloc((size_t)N * 4);
  int* bsum = (int*)alloc((size_t)((N + 255) / 256) * 4);
  int* ssrc = (int*)alloc((size_t)E * 4);

  const int NB = (N + 255) / 256;    // 391  (must be <= 512 for scan2par)
  const int EB = (E + 255) / 256;    // 6250
  const int GEMM_B = (N + 63) / 64;  // 1563
  const int NODE_B = (N + 3) / 4;    // 25000
  const int NK = N * IN_FEATS;

  detect_dtype<<<1, 256, 0, stream>>>((const u32*)features, 4096, dflag);

  // CSR by dst (shared by both layers)
  zero_i32<<<NB, 256, 0, stream>>>(counts, N);
  hist_kernel<<<EB, 256, 0, stream>>>(dst, counts, E);
  scan1<<<NB, 256, 0, stream>>>(counts, indptr, bsum, N);
  scan2par<<<1, 512, 0, stream>>>(bsum, NB);
  scan3<<<NB, 256, 0, stream>>>(indptr, bsum, cursor, N, E);
  scatter_kernel<<<EB, 256, 0, stream>>>(src, dst, cursor, ssrc, E);

  // features -> bf16
  conv_feat<<<(NK / 8 + 255) / 256, 256, 0, stream>>>(features, Xbf, NK, dflag);

  // layer 1
  bsw_build<<<((IN_FEATS / 32) * 8 * 64 + 255) / 256, 256, 0, stream>>>(W1, Bsw1, IN_FEATS, dflag);
  gemm_mfma<IN_FEATS><<<GEMM_B, 256, 0, stream>>>(Xbf, Bsw1, h, hb, N);
  el_er_kernel<<<NODE_B, 256, 0, stream>>>(h, al1, ar1, el, er, N, dflag);
  agg_kernel<0><<<NODE_B, 256, 0, stream>>>((const u32*)hb, el, er, indptr, ssrc, b1, (void*)x, N, dflag);

  // layer 2
  bsw_build<<<((HID / 32) * 8 * 64 + 255) / 256, 256, 0, stream>>>(W2, Bsw2, HID, dflag);
  gemm_mfma<HID><<<GEMM_B, 256, 0, stream>>>(x, Bsw2, h, hb, N);
  el_er_kernel<<<NODE_B, 256, 0, stream>>>(h, al2, ar2, el, er, N, dflag);
  agg_kernel<1><<<NODE_B, 256, 0, stream>>>((const u32*)hb, el, er, indptr, ssrc, b2, d_out, N, dflag);
}

// Round 4
// 621.770 us; speedup vs baseline: 1.4869x; 1.3233x over previous
//
#include <hip/hip_runtime.h>

typedef unsigned short u16;
typedef unsigned int u32;

#define NEG_SLOPE 0.2f

using short8 = __attribute__((ext_vector_type(8))) short;
using float4v = __attribute__((ext_vector_type(4))) float;

__device__ __forceinline__ float bfu(u16 v) { return __uint_as_float(((u32)v) << 16); }
__device__ __forceinline__ float bflo(u32 u) { return __uint_as_float(u << 16); }
__device__ __forceinline__ float bfhi(u32 u) { return __uint_as_float(u & 0xffff0000u); }
__device__ __forceinline__ u16 f2bf(float f) {
  u32 x = __float_as_uint(f);
  return (u16)((x + 0x7fffu + ((x >> 16) & 1u)) >> 16);
}
__device__ __forceinline__ float loadf(const void* p, int idx, int isbf) {
  return isbf ? bfu(((const u16*)p)[idx]) : ((const float*)p)[idx];
}

// ---------------- dtype detection (bf16 vs f32 inputs) ----------------
__global__ __launch_bounds__(256) void detect_dtype(const u32* __restrict__ w,
                                                    int nwords, int* __restrict__ flag) {
  __shared__ int cnt;
  if (threadIdx.x == 0) cnt = 0;
  __syncthreads();
  int c = 0;
  for (int i = threadIdx.x; i < nwords; i += 256) {
    u32 e = (w[i] >> 7) & 0xFFu;  // exponent of low-half-as-bf16
    c += (e >= 0x60u && e <= 0x90u) ? 1 : 0;
  }
  atomicAdd(&cnt, c);
  __syncthreads();
  if (threadIdx.x == 0) flag[0] = (cnt * 2 > nwords) ? 1 : 0;  // 1 = bf16
}

// ---------------- CSR build ----------------

__global__ __launch_bounds__(256) void zero_i32(int* __restrict__ p, int n) {
  int i = blockIdx.x * 256 + threadIdx.x;
  if (i < n) p[i] = 0;
}

__global__ __launch_bounds__(256) void hist_kernel(const int* __restrict__ dst,
                                                   int* __restrict__ counts, int E) {
  int e = blockIdx.x * 256 + threadIdx.x;
  if (e < E) atomicAdd(&counts[dst[e]], 1);
}

__global__ __launch_bounds__(256) void scan1(const int* __restrict__ counts,
                                             int* __restrict__ indptr,
                                             int* __restrict__ bsum, int N) {
  __shared__ int sh[256];
  int t = threadIdx.x;
  int idx = blockIdx.x * 256 + t;
  int v = (idx < N) ? counts[idx] : 0;
  sh[t] = v;
  __syncthreads();
  for (int off = 1; off < 256; off <<= 1) {
    int y = (t >= off) ? sh[t - off] : 0;
    __syncthreads();
    sh[t] += y;
    __syncthreads();
  }
  if (idx < N) indptr[idx] = sh[t] - v;  // exclusive, pre-offset
  if (t == 255) bsum[blockIdx.x] = sh[255];
}

// parallel single-block exclusive scan of block sums (NB <= 512)
__global__ __launch_bounds__(512) void scan2par(int* __restrict__ bsum, int NB) {
  __shared__ int sh[512];
  int t = threadIdx.x;
  int v = (t < NB) ? bsum[t] : 0;
  sh[t] = v;
  __syncthreads();
  for (int off = 1; off < 512; off <<= 1) {
    int y = (t >= off) ? sh[t - off] : 0;
    __syncthreads();
    sh[t] += y;
    __syncthreads();
  }
  if (t < NB) bsum[t] = sh[t] - v;  // exclusive
}

__global__ __launch_bounds__(256) void scan3(int* __restrict__ indptr,
                                             const int* __restrict__ boff,
                                             int* __restrict__ cursor, int N, int E) {
  int idx = blockIdx.x * 256 + threadIdx.x;
  if (idx < N) {
    int v = indptr[idx] + boff[blockIdx.x];
    indptr[idx] = v;
    cursor[idx] = v;
  }
  if (idx == 0) indptr[N] = E;
}

__global__ __launch_bounds__(256) void scatter_kernel(const int* __restrict__ src,
                                                      const int* __restrict__ dst,
                                                      int* __restrict__ cursor,
                                                      int* __restrict__ ssrc, int E) {
  int e = blockIdx.x * 256 + threadIdx.x;
  if (e < E) {
    int d = dst[e];
    int pos = atomicAdd(&cursor[d], 1);
    ssrc[pos] = src[e];
  }
}

// ---------------- B-fragment swizzle buffer ----------------
// Bsw[t][c][lane] : uint4 = 8 bf16, element j = B[k=t*32+(lane>>4)*8+j][n=c*16+(lane&15)]
// where B[k][n] = W[n][k] (W is [128][K] row-major, bf16 or f32 per dflag).
__global__ __launch_bounds__(256) void bsw_build(const void* __restrict__ W,
                                                 u16* __restrict__ Bsw, int K,
                                                 const int* __restrict__ dflag) {
  const int isbf = dflag[0];
  int t = blockIdx.x * 256 + threadIdx.x;
  int total = (K / 32) * 8 * 64;
  if (t >= total) return;
  int lane = t & 63;
  int c = (t >> 6) & 7;
  int ktile = t >> 9;
  int n = lane & 15, q = lane >> 4;
  int col = c * 16 + n;  // output-feature index (row of W)
  u16 vals[8];
#pragma unroll
  for (int j = 0; j < 8; ++j) {
    int k = ktile * 32 + q * 8 + j;
    int idx = col * K + k;
    vals[j] = isbf ? ((const u16*)W)[idx] : f2bf(((const float*)W)[idx]);
  }
  *(uint4*)(Bsw + (size_t)t * 8) = *(uint4*)vals;
}

// ---------------- MFMA GEMM + fused el/er ----------------
// H[N,128] = X[N,K] @ W^T. A read directly from X (bf16, or f32 per dflag when
// DYNA=1). Epilogue: Hb packed-bf16 row-major, plus el[n]=h.al, er[n]=h.ar
// from the f32 accumulators (quad shuffle-reduce).
template <int K, int DYNA>
__global__ __launch_bounds__(256) void gemm_mfma(const void* __restrict__ Xv,
                                                 const u16* __restrict__ Bsw,
                                                 u16* __restrict__ Hb,
                                                 const void* __restrict__ al,
                                                 const void* __restrict__ ar,
                                                 float* __restrict__ el_,
                                                 float* __restrict__ er_, int N,
                                                 const int* __restrict__ dflag) {
  const int isbfP = dflag[0];            // param dtype
  const int isbfA = DYNA ? isbfP : 1;    // A dtype (x is always bf16)
  int tid = threadIdx.x;
  int w = tid >> 6, lane = tid & 63;
  int n = lane & 15, q = lane >> 4;
  int row0 = blockIdx.x * 64 + w * 16;
  int m = row0 + n;
  int mclamp = (m < N) ? m : 0;  // OOB rows read row 0; outputs discarded

  float alv[8], arv[8];
#pragma unroll
  for (int c = 0; c < 8; ++c) {
    alv[c] = loadf(al, c * 16 + n, isbfP);
    arv[c] = loadf(ar, c * 16 + n, isbfP);
  }

  float4v acc[8];
#pragma unroll
  for (int c = 0; c < 8; ++c) acc[c] = (float4v){0.f, 0.f, 0.f, 0.f};

#pragma unroll
  for (int t = 0; t < K / 32; ++t) {
    short8 af;
    if (isbfA) {
      af = *(const short8*)((const u16*)Xv + (size_t)mclamp * K + t * 32 + q * 8);
    } else {
      const float* Af = (const float*)Xv + (size_t)mclamp * K + t * 32 + q * 8;
      float4 f0 = *(const float4*)Af;
      float4 f1 = *(const float4*)(Af + 4);
      u16 tmp[8] = {f2bf(f0.x), f2bf(f0.y), f2bf(f0.z), f2bf(f0.w),
                    f2bf(f1.x), f2bf(f1.y), f2bf(f1.z), f2bf(f1.w)};
      af = *(short8*)tmp;
    }
    const uint4* bt = (const uint4*)Bsw + ((size_t)t * 8) * 64 + lane;
#pragma unroll
    for (int c = 0; c < 8; ++c) {
      uint4 bw = bt[c * 64];
      short8 bf = *(short8*)&bw;
      acc[c] = __builtin_amdgcn_mfma_f32_16x16x32_bf16(af, bf, acc[c], 0, 0, 0);
    }
  }

  // Hb store: D layout col = c*16 + (lane&15), row = row0 + q*4 + r
#pragma unroll
  for (int c = 0; c < 8; ++c) {
#pragma unroll
    for (int r = 0; r < 4; ++r) {
      int row = row0 + q * 4 + r;
      if (row < N) Hb[(size_t)row * 128 + c * 16 + n] = f2bf(acc[c][r]);
    }
  }

  // fused el/er: reduce across the 16 lanes of each quad-row group
  float pl[4], pr[4];
#pragma unroll
  for (int r = 0; r < 4; ++r) {
    float sl = 0.f, sr = 0.f;
#pragma unroll
    for (int c = 0; c < 8; ++c) {
      float v = acc[c][r];
      sl = fmaf(v, alv[c], sl);
      sr = fmaf(v, arv[c], sr);
    }
#pragma unroll
    for (int off = 1; off < 16; off <<= 1) {
      sl += __shfl_xor(sl, off);
      sr += __shfl_xor(sr, off);
    }
    pl[r] = sl;
    pr[r] = sr;
  }
  if (n == 0) {
#pragma unroll
    for (int r = 0; r < 4; ++r) {
      int row = row0 + q * 4 + r;
      if (row < N) {
        el_[row] = pl[r];
        er_[row] = pr[r];
      }
    }
  }
}

// ---------------- aggregation: one wave per dst node, dual-stream online softmax ----
// Two independent online-softmax streams (even/odd edges) merged at the end;
// Hb/el loads issued one pair ahead, ssrc ids two pairs ahead -> ~6 loads in flight.
// MODE 0: x (packed bf16) = elu(agg + bias); MODE 1: d_out = agg + bias (dtype per flag).
template <int MODE>
__global__ __launch_bounds__(256) void agg_kernel(const u32* __restrict__ Hb,
                                                  const float* __restrict__ el,
                                                  const float* __restrict__ er,
                                                  const int* __restrict__ indptr,
                                                  const int* __restrict__ ssrc,
                                                  const void* __restrict__ bias,
                                                  void* __restrict__ outv, int N,
                                                  const int* __restrict__ dflag) {
  const int isbf = dflag[0];
  int tid = threadIdx.x;
  int n = blockIdx.x * 4 + (tid >> 6);
  int lane = tid & 63;
  if (n >= N) return;

  int beg = indptr[n];
  int end = indptr[n + 1];
  float ern = er[n];

  float mA = -INFINITY, lA = 0.f, a0A = 0.f, a1A = 0.f;
  float mB = -INFINITY, lB = 0.f, a0B = 0.f, a1B = 0.f;

  int p = beg;
  int s0 = (p < end) ? ssrc[p] : 0;
  int s1 = (p + 1 < end) ? ssrc[p + 1] : 0;
  int s2 = (p + 2 < end) ? ssrc[p + 2] : 0;
  int s3 = (p + 3 < end) ? ssrc[p + 3] : 0;
  float eA = el[s0], eB = el[s1];
  u32 hA = Hb[(size_t)s0 * 64 + lane];
  u32 hB = Hb[(size_t)s1 * 64 + lane];

  for (; p < end; p += 2) {
    // issue next-pair data loads (addresses already known)
    float eA2 = el[s2], eB2 = el[s3];
    u32 hA2 = Hb[(size_t)s2 * 64 + lane];
    u32 hB2 = Hb[(size_t)s3 * 64 + lane];
    // prefetch pair-after-next edge ids
    int s2n = (p + 4 < end) ? ssrc[p + 4] : 0;
    int s3n = (p + 5 < end) ? ssrc[p + 5] : 0;

    {  // stream A: edge p
      float sc = eA + ern;
      sc = (sc > 0.f) ? sc : NEG_SLOPE * sc;
      float mn = fmaxf(mA, sc);
      float corr = __expf(mA - mn), pe = __expf(sc - mn);
      lA = lA * corr + pe;
      a0A = a0A * corr + pe * bflo(hA);
      a1A = a1A * corr + pe * bfhi(hA);
      mA = mn;
    }
    if (p + 1 < end) {  // stream B: edge p+1 (wave-uniform predicate)
      float sc = eB + ern;
      sc = (sc > 0.f) ? sc : NEG_SLOPE * sc;
      float mn = fmaxf(mB, sc);
      float corr = __expf(mB - mn), pe = __expf(sc - mn);
      lB = lB * corr + pe;
      a0B = a0B * corr + pe * bflo(hB);
      a1B = a1B * corr + pe * bfhi(hB);
      mB = mn;
    }
    s2 = s2n; s3 = s3n;
    eA = eA2; eB = eB2; hA = hA2; hB = hB2;
  }

  // merge the two streams
  float mm = fmaxf(mA, mB);
  float ms = (mm > -INFINITY) ? mm : 0.f;  // avoid (-inf) - (-inf)
  float cA = __expf(mA - ms), cB = __expf(mB - ms);
  float l = lA * cA + lB * cB;
  float a0 = a0A * cA + a0B * cB;
  float a1 = a1A * cA + a1B * cB;
  float inv = (l > 0.f) ? 1.f / l : 0.f;
  float o0 = a0 * inv + loadf(bias, 2 * lane, isbf);
  float o1 = a1 * inv + loadf(bias, 2 * lane + 1, isbf);

  if (MODE == 0) {
    o0 = (o0 > 0.f) ? o0 : (__expf(o0) - 1.f);
    o1 = (o1 > 0.f) ? o1 : (__expf(o1) - 1.f);
    ((u32*)outv)[(size_t)n * 64 + lane] = (u32)f2bf(o0) | ((u32)f2bf(o1) << 16);
  } else {
    if (isbf) {
      ((u32*)outv)[(size_t)n * 64 + lane] = (u32)f2bf(o0) | ((u32)f2bf(o1) << 16);
    } else {
      ((float2*)outv)[(size_t)n * 64 + lane] = make_float2(o0, o1);
    }
  }
}

// ---------------- launch ----------------

extern "C" void kernel_launch(void* const* d_in, const int* in_sizes, int n_in,
                              void* d_out, int out_size, void* d_ws, size_t ws_size,
                              hipStream_t stream) {
  const int IN_FEATS = 256, HID = 128;
  const void* features = d_in[0];
  const int* src = (const int*)d_in[1];
  const int* dst = (const int*)d_in[2];
  const void* W1 = d_in[3];
  const void* al1 = d_in[4];
  const void* ar1 = d_in[5];
  const void* b1 = d_in[6];
  const void* W2 = d_in[7];
  const void* al2 = d_in[8];
  const void* ar2 = d_in[9];
  const void* b2 = d_in[10];

  const int N = in_sizes[0] / IN_FEATS;  // 100000
  const int E = in_sizes[1];             // 1600000

  char* p = (char*)d_ws;
  auto alloc = [&](size_t bytes) -> void* {
    void* q = (void*)p;
    p += (bytes + 255) & ~(size_t)255;
    return q;
  };
  int* dflag = (int*)alloc(256);
  u16* Bsw1 = (u16*)alloc((size_t)(IN_FEATS / 32) * 8 * 64 * 8 * 2);  // 64 KB
  u16* Bsw2 = (u16*)alloc((size_t)(HID / 32) * 8 * 64 * 8 * 2);       // 32 KB
  u16* hb = (u16*)alloc((size_t)N * HID * 2);  // 25.6 MB
  u16* x = (u16*)alloc((size_t)N * HID * 2);   // 25.6 MB
  float* el = (float*)alloc((size_t)N * 4);
  float* er = (float*)alloc((size_t)N * 4);
  int* counts = (int*)alloc((size_t)N * 4);
  int* indptr = (int*)alloc((size_t)(N + 1) * 4);
  int* cursor = (int*)alloc((size_t)N * 4);
  int* bsum = (int*)alloc((size_t)((N + 255) / 256) * 4);
  int* ssrc = (int*)alloc((size_t)E * 4);

  const int NB = (N + 255) / 256;    // 391 (<= 512 for scan2par)
  const int EB = (E + 255) / 256;    // 6250
  const int GEMM_B = (N + 63) / 64;  // 1563
  const int NODE_B = (N + 3) / 4;    // 25000

  detect_dtype<<<1, 256, 0, stream>>>((const u32*)features, 4096, dflag);

  // CSR by dst (shared by both layers)
  zero_i32<<<NB, 256, 0, stream>>>(counts, N);
  hist_kernel<<<EB, 256, 0, stream>>>(dst, counts, E);
  scan1<<<NB, 256, 0, stream>>>(counts, indptr, bsum, N);
  scan2par<<<1, 512, 0, stream>>>(bsum, NB);
  scan3<<<NB, 256, 0, stream>>>(indptr, bsum, cursor, N, E);
  scatter_kernel<<<EB, 256, 0, stream>>>(src, dst, cursor, ssrc, E);

  // layer 1: GEMM (direct feature read) + fused el/er
  bsw_build<<<((IN_FEATS / 32) * 8 * 64 + 255) / 256, 256, 0, stream>>>(W1, Bsw1, IN_FEATS, dflag);
  gemm_mfma<IN_FEATS, 1><<<GEMM_B, 256, 0, stream>>>(features, Bsw1, hb, al1, ar1, el, er, N, dflag);
  agg_kernel<0><<<NODE_B, 256, 0, stream>>>((const u32*)hb, el, er, indptr, ssrc, b1, (void*)x, N, dflag);

  // layer 2
  bsw_build<<<((HID / 32) * 8 * 64 + 255) / 256, 256, 0, stream>>>(W2, Bsw2, HID, dflag);
  gemm_mfma<HID, 0><<<GEMM_B, 256, 0, stream>>>((const void*)x, Bsw2, hb, al2, ar2, el, er, N, dflag);
  agg_kernel<1><<<NODE_B, 256, 0, stream>>>((const u32*)hb, el, er, indptr, ssrc, b2, d_out, N, dflag);
}

// Round 5
// 520.801 us; speedup vs baseline: 1.7751x; 1.1939x over previous
//
#include <hip/hip_runtime.h>

typedef unsigned short u16;
typedef unsigned int u32;

#define NEG_SLOPE 0.2f

using short8 = __attribute__((ext_vector_type(8))) short;
using float4v = __attribute__((ext_vector_type(4))) float;

__device__ __forceinline__ float bfu(u16 v) { return __uint_as_float(((u32)v) << 16); }
__device__ __forceinline__ float bflo(u32 u) { return __uint_as_float(u << 16); }
__device__ __forceinline__ float bfhi(u32 u) { return __uint_as_float(u & 0xffff0000u); }
__device__ __forceinline__ u16 f2bf(float f) {
  u32 x = __float_as_uint(f);
  return (u16)((x + 0x7fffu + ((x >> 16) & 1u)) >> 16);
}
__device__ __forceinline__ float loadf(const void* p, int idx, int isbf) {
  return isbf ? bfu(((const u16*)p)[idx]) : ((const float*)p)[idx];
}

// ---------------- dtype detection (bf16 vs f32 inputs) ----------------
__global__ __launch_bounds__(256) void detect_dtype(const u32* __restrict__ w,
                                                    int nwords, int* __restrict__ flag) {
  __shared__ int cnt;
  if (threadIdx.x == 0) cnt = 0;
  __syncthreads();
  int c = 0;
  for (int i = threadIdx.x; i < nwords; i += 256) {
    u32 e = (w[i] >> 7) & 0xFFu;  // exponent of low-half-as-bf16
    c += (e >= 0x60u && e <= 0x90u) ? 1 : 0;
  }
  atomicAdd(&cnt, c);
  __syncthreads();
  if (threadIdx.x == 0) flag[0] = (cnt * 2 > nwords) ? 1 : 0;  // 1 = bf16
}

__global__ __launch_bounds__(256) void zero_i32(int* __restrict__ p, int n) {
  int i = blockIdx.x * 256 + threadIdx.x;
  if (i < n) p[i] = 0;
}

// ---------------- scans ----------------

__global__ __launch_bounds__(256) void scan1(const int* __restrict__ counts,
                                             int* __restrict__ indptr,
                                             int* __restrict__ bsum, int N) {
  __shared__ int sh[256];
  int t = threadIdx.x;
  int idx = blockIdx.x * 256 + t;
  int v = (idx < N) ? counts[idx] : 0;
  sh[t] = v;
  __syncthreads();
  for (int off = 1; off < 256; off <<= 1) {
    int y = (t >= off) ? sh[t - off] : 0;
    __syncthreads();
    sh[t] += y;
    __syncthreads();
  }
  if (idx < N) indptr[idx] = sh[t] - v;  // exclusive, pre-offset
  if (t == 255) bsum[blockIdx.x] = sh[255];
}

// parallel single-block exclusive scan of block sums (NB <= 512)
__global__ __launch_bounds__(512) void scan2par(int* __restrict__ bsum, int NB) {
  __shared__ int sh[512];
  int t = threadIdx.x;
  int v = (t < NB) ? bsum[t] : 0;
  sh[t] = v;
  __syncthreads();
  for (int off = 1; off < 512; off <<= 1) {
    int y = (t >= off) ? sh[t - off] : 0;
    __syncthreads();
    sh[t] += y;
    __syncthreads();
  }
  if (t < NB) bsum[t] = sh[t] - v;  // exclusive
}

__global__ __launch_bounds__(256) void scan3(int* __restrict__ indptr,
                                             const int* __restrict__ boff,
                                             int N, int E) {
  int idx = blockIdx.x * 256 + threadIdx.x;
  if (idx < N) indptr[idx] += boff[blockIdx.x];
  if (idx == 0) indptr[N] = E;
}

// ---------------- scatter without atomics (uses precomputed rank) ----------------
__global__ __launch_bounds__(256) void scatter2(const int* __restrict__ src,
                                                const int* __restrict__ dst,
                                                const int* __restrict__ rank,
                                                const int* __restrict__ indptr,
                                                int* __restrict__ ssrc, int E) {
  int e = blockIdx.x * 256 + threadIdx.x;
  if (e < E) {
    int d = dst[e];
    ssrc[indptr[d] + rank[e]] = src[e];
  }
}

// ---------------- B-fragment swizzle buffer ----------------
// Bsw[t][c][lane] : uint4 = 8 bf16, element j = B[k=t*32+(lane>>4)*8+j][n=c*16+(lane&15)]
// where B[k][n] = W[n][k] (W is [128][K] row-major, bf16 or f32 per dflag).
__global__ __launch_bounds__(256) void bsw_build(const void* __restrict__ W,
                                                 u16* __restrict__ Bsw, int K,
                                                 const int* __restrict__ dflag) {
  const int isbf = dflag[0];
  int t = blockIdx.x * 256 + threadIdx.x;
  int total = (K / 32) * 8 * 64;
  if (t >= total) return;
  int lane = t & 63;
  int c = (t >> 6) & 7;
  int ktile = t >> 9;
  int n = lane & 15, q = lane >> 4;
  int col = c * 16 + n;
  u16 vals[8];
#pragma unroll
  for (int j = 0; j < 8; ++j) {
    int k = ktile * 32 + q * 8 + j;
    int idx = col * K + k;
    vals[j] = isbf ? ((const u16*)W)[idx] : f2bf(((const float*)W)[idx]);
  }
  *(uint4*)(Bsw + (size_t)t * 8) = *(uint4*)vals;
}

// ---------------- MFMA GEMM body (device fn) + fused el/er epilogue ----------------
template <int K, int DYNA>
__device__ __forceinline__ void gemm_body(int bix, const void* __restrict__ Xv,
                                          const u16* __restrict__ Bsw,
                                          u16* __restrict__ Hb,
                                          const void* __restrict__ al,
                                          const void* __restrict__ ar,
                                          float* __restrict__ el_,
                                          float* __restrict__ er_, int N,
                                          const int* __restrict__ dflag) {
  const int isbfP = dflag[0];
  const int isbfA = DYNA ? isbfP : 1;  // x intermediate is always bf16
  int tid = threadIdx.x;
  int w = tid >> 6, lane = tid & 63;
  int n = lane & 15, q = lane >> 4;
  int row0 = bix * 64 + w * 16;
  int m = row0 + n;
  int mclamp = (m < N) ? m : 0;

  float alv[8], arv[8];
#pragma unroll
  for (int c = 0; c < 8; ++c) {
    alv[c] = loadf(al, c * 16 + n, isbfP);
    arv[c] = loadf(ar, c * 16 + n, isbfP);
  }

  float4v acc[8];
#pragma unroll
  for (int c = 0; c < 8; ++c) acc[c] = (float4v){0.f, 0.f, 0.f, 0.f};

#pragma unroll
  for (int t = 0; t < K / 32; ++t) {
    short8 af;
    if (isbfA) {
      af = *(const short8*)((const u16*)Xv + (size_t)mclamp * K + t * 32 + q * 8);
    } else {
      const float* Af = (const float*)Xv + (size_t)mclamp * K + t * 32 + q * 8;
      float4 f0 = *(const float4*)Af;
      float4 f1 = *(const float4*)(Af + 4);
      u16 tmp[8] = {f2bf(f0.x), f2bf(f0.y), f2bf(f0.z), f2bf(f0.w),
                    f2bf(f1.x), f2bf(f1.y), f2bf(f1.z), f2bf(f1.w)};
      af = *(short8*)tmp;
    }
    const uint4* bt = (const uint4*)Bsw + ((size_t)t * 8) * 64 + lane;
#pragma unroll
    for (int c = 0; c < 8; ++c) {
      uint4 bw = bt[c * 64];
      short8 bf = *(short8*)&bw;
      acc[c] = __builtin_amdgcn_mfma_f32_16x16x32_bf16(af, bf, acc[c], 0, 0, 0);
    }
  }

  // Hb store: D layout col = c*16 + (lane&15), row = row0 + q*4 + r
#pragma unroll
  for (int c = 0; c < 8; ++c) {
#pragma unroll
    for (int r = 0; r < 4; ++r) {
      int row = row0 + q * 4 + r;
      if (row < N) Hb[(size_t)row * 128 + c * 16 + n] = f2bf(acc[c][r]);
    }
  }

  // fused el/er: reduce across the 16 lanes of each quad-row group
#pragma unroll
  for (int r = 0; r < 4; ++r) {
    float sl = 0.f, sr = 0.f;
#pragma unroll
    for (int c = 0; c < 8; ++c) {
      float v = acc[c][r];
      sl = fmaf(v, alv[c], sl);
      sr = fmaf(v, arv[c], sr);
    }
#pragma unroll
    for (int off = 1; off < 16; off <<= 1) {
      sl += __shfl_xor(sl, off);
      sr += __shfl_xor(sr, off);
    }
    if (n == 0) {
      int row = row0 + q * 4 + r;
      if (row < N) {
        el_[row] = sl;
        er_[row] = sr;
      }
    }
  }
}

// standalone GEMM (layer 2)
template <int K, int DYNA>
__global__ __launch_bounds__(256) void gemm_mfma(const void* __restrict__ Xv,
                                                 const u16* __restrict__ Bsw,
                                                 u16* __restrict__ Hb,
                                                 const void* __restrict__ al,
                                                 const void* __restrict__ ar,
                                                 float* __restrict__ el_,
                                                 float* __restrict__ er_, int N,
                                                 const int* __restrict__ dflag) {
  gemm_body<K, DYNA>(blockIdx.x, Xv, Bsw, Hb, al, ar, el_, er_, N, dflag);
}

// fused: blocks [0, gemm_blocks) do GEMM layer 1; the rest do hist+rank.
// Independent data; no barriers on either path.
template <int K, int DYNA>
__global__ __launch_bounds__(256) void fused_gemm_hist(
    const void* __restrict__ Xv, const u16* __restrict__ Bsw, u16* __restrict__ Hb,
    const void* __restrict__ al, const void* __restrict__ ar,
    float* __restrict__ el_, float* __restrict__ er_, int N,
    const int* __restrict__ dflag, int gemm_blocks,
    const int* __restrict__ dst, int* __restrict__ counts,
    int* __restrict__ rank, int E) {
  int bix = (int)blockIdx.x;
  if (bix < gemm_blocks) {
    gemm_body<K, DYNA>(bix, Xv, Bsw, Hb, al, ar, el_, er_, N, dflag);
  } else {
    int e = (bix - gemm_blocks) * 256 + threadIdx.x;
    if (e < E) rank[e] = atomicAdd(&counts[dst[e]], 1);
  }
}

// ---------------- aggregation: one wave per dst, 4-stream online softmax ----------
// 4 independent streams; data loads one group ahead, edge ids two groups ahead
// -> ~12 outstanding loads per wave.
// MODE 0: x (packed bf16) = elu(agg + bias); MODE 1: d_out = agg + bias.
template <int MODE>
__global__ __launch_bounds__(256) void agg_kernel(const u32* __restrict__ Hb,
                                                  const float* __restrict__ el,
                                                  const float* __restrict__ er,
                                                  const int* __restrict__ indptr,
                                                  const int* __restrict__ ssrc,
                                                  const void* __restrict__ bias,
                                                  void* __restrict__ outv, int N,
                                                  const int* __restrict__ dflag) {
  const int isbf = dflag[0];
  int tid = threadIdx.x;
  int n = blockIdx.x * 4 + (tid >> 6);
  int lane = tid & 63;
  if (n >= N) return;

  int beg = indptr[n];
  int end = indptr[n + 1];
  float ern = er[n];

  float ms[4], ll[4], aa0[4], aa1[4];
#pragma unroll
  for (int j = 0; j < 4; ++j) {
    ms[j] = -INFINITY; ll[j] = 0.f; aa0[j] = 0.f; aa1[j] = 0.f;
  }

  int p = beg;
  int id[8];
#pragma unroll
  for (int j = 0; j < 8; ++j) id[j] = (p + j < end) ? ssrc[p + j] : 0;
  float ev[4];
  u32 hv[4];
#pragma unroll
  for (int j = 0; j < 4; ++j) {
    ev[j] = el[id[j]];
    hv[j] = Hb[(size_t)id[j] * 64 + lane];
  }

  for (; p < end; p += 4) {
    // prefetch data for next group
    float ev2[4];
    u32 hv2[4];
#pragma unroll
    for (int j = 0; j < 4; ++j) {
      ev2[j] = el[id[4 + j]];
      hv2[j] = Hb[(size_t)id[4 + j] * 64 + lane];
    }
    // prefetch ids for group after next
    int idn[4];
#pragma unroll
    for (int j = 0; j < 4; ++j) idn[j] = (p + 8 + j < end) ? ssrc[p + 8 + j] : 0;

    // process current group (wave-uniform predicates)
#pragma unroll
    for (int j = 0; j < 4; ++j) {
      if (p + j < end) {
        float sc = ev[j] + ern;
        sc = (sc > 0.f) ? sc : NEG_SLOPE * sc;
        float mn = fmaxf(ms[j], sc);
        float corr = __expf(ms[j] - mn), pe = __expf(sc - mn);
        ll[j] = ll[j] * corr + pe;
        aa0[j] = aa0[j] * corr + pe * bflo(hv[j]);
        aa1[j] = aa1[j] * corr + pe * bfhi(hv[j]);
        ms[j] = mn;
      }
    }
#pragma unroll
    for (int j = 0; j < 4; ++j) {
      id[j] = id[4 + j];
      id[4 + j] = idn[j];
      ev[j] = ev2[j];
      hv[j] = hv2[j];
    }
  }

  // merge the four streams
  float mm = fmaxf(fmaxf(ms[0], ms[1]), fmaxf(ms[2], ms[3]));
  float msafe = (mm > -INFINITY) ? mm : 0.f;
  float l = 0.f, a0 = 0.f, a1 = 0.f;
#pragma unroll
  for (int j = 0; j < 4; ++j) {
    float c = __expf(ms[j] - msafe);  // exp(-inf)=0 for empty streams
    l += ll[j] * c;
    a0 += aa0[j] * c;
    a1 += aa1[j] * c;
  }
  float inv = (l > 0.f) ? 1.f / l : 0.f;
  float o0 = a0 * inv + loadf(bias, 2 * lane, isbf);
  float o1 = a1 * inv + loadf(bias, 2 * lane + 1, isbf);

  if (MODE == 0) {
    o0 = (o0 > 0.f) ? o0 : (__expf(o0) - 1.f);
    o1 = (o1 > 0.f) ? o1 : (__expf(o1) - 1.f);
    ((u32*)outv)[(size_t)n * 64 + lane] = (u32)f2bf(o0) | ((u32)f2bf(o1) << 16);
  } else {
    if (isbf) {
      ((u32*)outv)[(size_t)n * 64 + lane] = (u32)f2bf(o0) | ((u32)f2bf(o1) << 16);
    } else {
      ((float2*)outv)[(size_t)n * 64 + lane] = make_float2(o0, o1);
    }
  }
}

// ---------------- launch ----------------

extern "C" void kernel_launch(void* const* d_in, const int* in_sizes, int n_in,
                              void* d_out, int out_size, void* d_ws, size_t ws_size,
                              hipStream_t stream) {
  const int IN_FEATS = 256, HID = 128;
  const void* features = d_in[0];
  const int* src = (const int*)d_in[1];
  const int* dst = (const int*)d_in[2];
  const void* W1 = d_in[3];
  const void* al1 = d_in[4];
  const void* ar1 = d_in[5];
  const void* b1 = d_in[6];
  const void* W2 = d_in[7];
  const void* al2 = d_in[8];
  const void* ar2 = d_in[9];
  const void* b2 = d_in[10];

  const int N = in_sizes[0] / IN_FEATS;  // 100000
  const int E = in_sizes[1];             // 1600000

  char* p = (char*)d_ws;
  auto alloc = [&](size_t bytes) -> void* {
    void* q = (void*)p;
    p += (bytes + 255) & ~(size_t)255;
    return q;
  };
  int* dflag = (int*)alloc(256);
  u16* Bsw1 = (u16*)alloc((size_t)(IN_FEATS / 32) * 8 * 64 * 8 * 2);  // 64 KB
  u16* Bsw2 = (u16*)alloc((size_t)(HID / 32) * 8 * 64 * 8 * 2);       // 32 KB
  u16* hb = (u16*)alloc((size_t)N * HID * 2);  // 25.6 MB
  u16* x = (u16*)alloc((size_t)N * HID * 2);   // 25.6 MB
  float* el = (float*)alloc((size_t)N * 4);
  float* er = (float*)alloc((size_t)N * 4);
  int* counts = (int*)alloc((size_t)N * 4);
  int* indptr = (int*)alloc((size_t)(N + 1) * 4);
  int* rank = (int*)alloc((size_t)E * 4);      // 6.4 MB
  int* bsum = (int*)alloc((size_t)((N + 255) / 256) * 4);
  int* ssrc = (int*)alloc((size_t)E * 4);

  const int NB = (N + 255) / 256;    // 391 (<= 512 for scan2par)
  const int EB = (E + 255) / 256;    // 6250
  const int GEMM_B = (N + 63) / 64;  // 1563
  const int NODE_B = (N + 3) / 4;    // 25000

  detect_dtype<<<1, 256, 0, stream>>>((const u32*)features, 4096, dflag);
  zero_i32<<<NB, 256, 0, stream>>>(counts, N);
  bsw_build<<<((IN_FEATS / 32) * 8 * 64 + 255) / 256, 256, 0, stream>>>(W1, Bsw1, IN_FEATS, dflag);
  bsw_build<<<((HID / 32) * 8 * 64 + 255) / 256, 256, 0, stream>>>(W2, Bsw2, HID, dflag);

  // GEMM layer 1 (+ fused el/er) co-scheduled with hist+rank (independent work)
  fused_gemm_hist<IN_FEATS, 1><<<GEMM_B + EB, 256, 0, stream>>>(
      features, Bsw1, hb, al1, ar1, el, er, N, dflag, GEMM_B, dst, counts, rank, E);

  scan1<<<NB, 256, 0, stream>>>(counts, indptr, bsum, N);
  scan2par<<<1, 512, 0, stream>>>(bsum, NB);
  scan3<<<NB, 256, 0, stream>>>(indptr, bsum, N, E);
  scatter2<<<EB, 256, 0, stream>>>(src, dst, rank, indptr, ssrc, E);

  agg_kernel<0><<<NODE_B, 256, 0, stream>>>((const u32*)hb, el, er, indptr, ssrc, b1, (void*)x, N, dflag);

  gemm_mfma<HID, 0><<<GEMM_B, 256, 0, stream>>>((const void*)x, Bsw2, hb, al2, ar2, el, er, N, dflag);
  agg_kernel<1><<<NODE_B, 256, 0, stream>>>((const u32*)hb, el, er, indptr, ssrc, b2, d_out, N, dflag);
}